// Round 4
// baseline (238.101 us; speedup 1.0000x reference)
//
#include <hip/hip_runtime.h>

// ---------------- problem constants ----------------
#define NROI  100
#define NB    4          // 400/100 diagonal blocks
#define NEDGE 160000
#define RESN  1000
#define SAMP  50
#define BREP  8          // batch tiling (B=8)
#define MDEG  44         // effective polynomial rank cutoff
#define NMODE (MDEG + 1)
#define BIGF  1.0e9f
#define PAIR_CAP 5056    // >= 100*99/2 - 99 masked pairs

// ---------------- static device workspace ----------------
struct WS0 { float adj[NB * NROI * NROI]; int bnz; };
__device__ WS0  g_ws0;                    // zeroed by one hipMemsetAsync
__device__ float g_D[NB * NROI * NROI];
__device__ float g_death1[NB * NROI * NROI];
__device__ float g_betti[NB * RESN];
__device__ float g_pb[NB][PAIR_CAP];
__device__ float g_pd[NB][PAIR_CAP];
__device__ int   g_pcnt[NB];
__device__ float g_smin[NB], g_smax[NB];
__device__ double g_q[NMODE][RESN];  // orthonormal poly basis values
__device__ double g_qd[NMODE][RESN]; // derivatives d/dx

// ---------------- helpers ----------------
__device__ inline double wave_sum_f64(double p) {
    for (int off = 32; off > 0; off >>= 1) p += __shfl_xor(p, off, 64);
    return p;
}
__device__ inline unsigned int rdlane(unsigned int v, int lane) {
    return (unsigned int)__builtin_amdgcn_readlane((int)v, lane);
}

// ---------------- 1) scatter-add diagonal-block edges ----------------
__global__ void k_scatter(const int* __restrict__ ei, const float* __restrict__ ea) {
    const int e = blockIdx.x * blockDim.x + threadIdx.x;
    if (e >= NEDGE) return;
    const int r = ei[e], c = ei[NEDGE + e];
    const int br = r / NROI, bc = c / NROI;
    if (br == bc)
        atomicAdd(&g_ws0.adj[br * NROI * NROI + (r - br * NROI) * NROI + (c - bc * NROI)], ea[e]);
}

// ---------------- 2) fused: D = max(1-adj,0) elementwise + H1 deaths ----------------
// death1[i,j] = max(D_ij, min_k!=i,j max(D_ik, D_jk)); fmin/fmax exact -> assoc-free.
__device__ inline float dclamp(float a) { const float d = 1.f - a; return d > 0.f ? d : 0.f; }
__global__ void k_death1() {
    const int tid = blockIdx.x * blockDim.x + threadIdx.x;
    if (tid >= NB * NROI * NROI) return;
    const int b  = tid / (NROI * NROI);
    const int ij = tid % (NROI * NROI);
    const int i = ij / NROI, j = ij % NROI;
    const float* __restrict__ ai = g_ws0.adj + b * NROI * NROI + i * NROI;
    const float* __restrict__ aj = g_ws0.adj + b * NROI * NROI + j * NROI;
    float Tm = BIGF;
    float dij = 0.f;
    for (int k = 0; k < NROI; k += 4) {
        const float4 a = *(const float4*)(ai + k);
        const float4 c = *(const float4*)(aj + k);
        const float di0 = dclamp(a.x), di1 = dclamp(a.y), di2 = dclamp(a.z), di3 = dclamp(a.w);
        const float dj0 = dclamp(c.x), dj1 = dclamp(c.y), dj2 = dclamp(c.z), dj3 = dclamp(c.w);
        float m0 = (k + 0 == i || k + 0 == j) ? BIGF : fmaxf(di0, dj0);
        float m1 = (k + 1 == i || k + 1 == j) ? BIGF : fmaxf(di1, dj1);
        float m2 = (k + 2 == i || k + 2 == j) ? BIGF : fmaxf(di2, dj2);
        float m3 = (k + 3 == i || k + 3 == j) ? BIGF : fmaxf(di3, dj3);
        Tm = fminf(Tm, fminf(fminf(m0, m1), fminf(m2, m3)));
        if (j >= k && j < k + 4) dij = (j == k) ? di0 : (j == k + 1) ? di1 : (j == k + 2) ? di2 : di3;
    }
    g_D[tid]      = dij;
    g_death1[tid] = fmaxf(dij, Tm);
}

// ---------------- 3) single-wave Prim; zero-candidate bitmask chain (no LDS on chain) ----------------
__global__ void __launch_bounds__(64) k_prim() {
    const int b = blockIdx.x, lane = threadIdx.x;
    const float* __restrict__ Db = g_D + b * NROI * NROI;
    __shared__ float Dl[NROI * NROI];
    __shared__ float deathsL[NROI - 1];
    __shared__ int   vsL[NROI - 1], usL[NROI - 1];
    __shared__ int   parL[NROI];
    __shared__ unsigned char mstL[NROI * NROI];
    __shared__ int cntL;
    // stage D into LDS (2500 float4)
    for (int i = lane; i < NROI * NROI / 4; i += 64)
        ((float4*)Dl)[i] = ((const float4*)Db)[i];
    for (int i = lane; i < NROI * NROI / 4; i += 64) ((unsigned int*)mstL)[i] = 0;
    for (int s = lane; s < NROI - 1; s += 64) { deathsL[s] = 0.f; usL[s] = 0; }
    if (lane == 0) cntL = 0;
    __syncthreads();

    const int  i1   = 64 + lane;
    const bool has1 = (i1 < NROI);
    // per-lane zero-row bitmasks: z0 = row 'lane', z1 = row 'lane+64' (bits over columns t)
    unsigned int z0[4] = {0, 0, 0, 0}, z1[4] = {0, 0, 0, 0};
    for (int k = 0; k < NROI; ++k) {
        if (Dl[lane * NROI + k] == 0.f) z0[k >> 5] |= 1u << (k & 31);
        if (has1 && Dl[i1 * NROI + k] == 0.f) z1[k >> 5] |= 1u << (k & 31);
    }
    __syncthreads();

    // scalar state: candidate mask C (nodes with a zero edge from tree), tree mask T
    unsigned long long Clo, Chi, Tlo = 1ull, Thi = 0ull;
    {   // row 0 lives in lane 0's z0
        const unsigned int a0 = rdlane(z0[0], 0), a1 = rdlane(z0[1], 0);
        const unsigned int a2 = rdlane(z0[2], 0), a3 = rdlane(z0[3], 0);
        Clo = ((unsigned long long)a1 << 32) | a0;
        Chi = ((unsigned long long)a3 << 32) | a2;
    }
    bool it0 = (lane == 0), it1 = false;
    bool cand0 = (Clo >> lane) & 1ull;                 // mind==0 now
    bool cand1 = has1 ? ((Chi >> lane) & 1ull) : false;
    int  par0 = 0, par1 = 0;                           // first zero-offerer (frozen once cand)

    for (int step = 0; step < NROI - 1; ++step) {
        const unsigned long long alo = Clo & ~Tlo, ahi = Chi & ~Thi;
        int j;
        if (alo | ahi) {
            // jnp.argmin first-index == first not-in-tree node with mind==0 (D >= 0 always)
            j = alo ? (__ffsll(alo) - 1) : (63 + __ffsll(ahi));
        } else {
            // general fallback: replay mind/parent over tree insertion order, exact butterfly argmin
            float m0 = Dl[lane]; int p0 = 0;
            float m1 = has1 ? Dl[i1] : BIGF; int p1 = 0;
            for (int s = 0; s < step; ++s) {
                const int q = vsL[s];
                const float d0 = Dl[q * NROI + lane];
                if (d0 < m0) { m0 = d0; p0 = q; }     // strict <, as reference
                if (has1) {
                    const float d1 = Dl[q * NROI + i1];
                    if (d1 < m1) { m1 = d1; p1 = q; }
                }
            }
            const float v0 = it0 ? BIGF : m0;
            const float v1 = (has1 && !it1) ? m1 : BIGF;
            float vv; int idx, pw;
            if (v0 <= v1) { vv = v0; idx = lane; pw = p0; } else { vv = v1; idx = i1; pw = p1; }
            #pragma unroll
            for (int off = 1; off < 64; off <<= 1) {
                const float ov = __shfl_xor(vv, off, 64);
                const int   oi = __shfl_xor(idx, off, 64);
                const int   op = __shfl_xor(pw, off, 64);
                if (ov < vv || (ov == vv && oi < idx)) { vv = ov; idx = oi; pw = op; }
            }
            j = idx;
            if (lane == 0) { deathsL[step] = vv; usL[step] = pw; }
        }
        if (lane == 0) vsL[step] = j;
        if (j < 64) Tlo |= 1ull << j; else Thi |= 1ull << (j - 64);
        if (lane == j) it0 = true;
        if (i1 == j)   it1 = true;
        // fetch row j's zero bits from the owning lane's registers (VALU, not LDS)
        const int jl = j & 63;
        unsigned int r0, r1, r2, r3;
        if (j < 64) { r0 = rdlane(z0[0], jl); r1 = rdlane(z0[1], jl); r2 = rdlane(z0[2], jl); r3 = rdlane(z0[3], jl); }
        else        { r0 = rdlane(z1[0], jl); r1 = rdlane(z1[1], jl); r2 = rdlane(z1[2], jl); r3 = rdlane(z1[3], jl); }
        const unsigned long long rlo = ((unsigned long long)r1 << 32) | r0;
        const unsigned long long rhi = ((unsigned long long)r3 << 32) | r2;
        Clo |= rlo; Chi |= rhi;
        // parent = first zero-offerer; frozen once candidate; in-tree nodes never update
        const bool bit0 = (rlo >> lane) & 1ull;
        if (bit0 && !cand0 && !it0) { par0 = j; cand0 = true; }
        if (has1) {
            const bool bit1 = (rhi >> lane) & 1ull;
            if (bit1 && !cand1 && !it1) { par1 = j; cand1 = true; }
        }
    }
    // final parents -> LDS, then resolve u per step and build MST bitmap
    parL[lane] = par0;
    if (has1) parL[i1] = par1;
    __syncthreads();
    for (int s = lane; s < NROI - 1; s += 64) {
        const int j = vsL[s];
        const int u = (deathsL[s] > 0.f) ? usL[s] : parL[j];  // zero-death => parent frozen at first-zero-offerer
        mstL[u * NROI + j] = 1;
        mstL[j * NROI + u] = 1;
    }
    __syncthreads();

    // masked pair compaction + smin/smax
    float mn = BIGF, mx = -BIGF;
    for (int e = lane; e < NROI * NROI; e += 64) {
        const int i = e / NROI, jj = e % NROI;
        if (i < jj && !mstL[e]) {
            const float bv = Dl[e];
            const float dv = g_death1[b * NROI * NROI + e];
            mn = fminf(mn, bv); mx = fmaxf(mx, dv);
            const int pos = atomicAdd(&cntL, 1);
            g_pb[b][pos] = bv; g_pd[b][pos] = dv;
        }
    }
    #pragma unroll
    for (int off = 1; off < 64; off <<= 1) {
        mn = fminf(mn, __shfl_xor(mn, off, 64));
        mx = fmaxf(mx, __shfl_xor(mx, off, 64));
    }
    __syncthreads();
    if (lane == 0) { g_smin[b] = mn; g_smax[b] = mx; g_pcnt[b] = cntL; }

    // dmax + betti (H0)
    float dmax = -1.f;
    for (int s = lane; s < NROI - 1; s += 64) dmax = fmaxf(dmax, deathsL[s]);
    #pragma unroll
    for (int off = 1; off < 64; off <<= 1) dmax = fmaxf(dmax, __shfl_xor(dmax, off, 64));
    const float stepg = dmax / 999.0f;       // f32 linspace step, start = 0
    for (int tt = lane; tt < RESN; tt += 64) {
        const float g = (tt == RESN - 1) ? dmax : (float)tt * stepg;
        int cnt2 = 0;
        for (int s2 = 0; s2 < NROI - 1; ++s2) cnt2 += (g < deathsL[s2]) ? 1 : 0;
        g_betti[b * RESN + tt] = (float)cnt2;
    }
    if (lane == 0 && dmax > 0.f) atomicOr(&g_ws0.bnz, 1);
}

// ---------------- 4) orthonormal polynomial basis (skipped when betti==0) ----------------
__global__ void __launch_bounds__(1024) k_basis() {
    if (g_ws0.bnz == 0) return;   // degenerate H0 branch: fit is exactly zero, basis unused
    const int t = threadIdx.x;
    const int lane = t & 63, wv = t >> 6;  // 16 waves
    __shared__ double xs[RESN];
    __shared__ double w[RESN], dwv[RESN];
    __shared__ double cj[NMODE], ctot[NMODE];
    __shared__ double red[16];
    if (t < RESN) {
        xs[t] = (2.0 * (double)t - 999.0) / 999.0;
        const double q0 = 1.0 / sqrt(1000.0);
        g_q[0][t] = q0;
        g_qd[0][t] = 0.0;
    }
    __syncthreads();
    for (int k = 0; k < MDEG; ++k) {
        if (t < RESN) {
            w[t]   = xs[t] * g_q[k][t];
            dwv[t] = g_q[k][t] + xs[t] * g_qd[k][t];
        }
        if (t < NMODE) ctot[t] = 0.0;
        __syncthreads();
        for (int round = 0; round < 2; ++round) {   // CGS twice == stable
            for (int j = wv; j <= k; j += 16) {
                double p = 0.0;
                for (int tt = lane; tt < RESN; tt += 64) p += w[tt] * g_q[j][tt];
                p = wave_sum_f64(p);
                if (lane == 0) cj[j] = p;
            }
            __syncthreads();
            if (t < RESN) {
                double acc = w[t];
                for (int j = 0; j <= k; ++j) acc -= cj[j] * g_q[j][t];
                w[t] = acc;
            }
            if (t <= k) ctot[t] += cj[t];
            __syncthreads();
        }
        if (t < RESN) {
            double acc = dwv[t];
            for (int j = 0; j <= k; ++j) acc -= ctot[j] * g_qd[j][t];
            dwv[t] = acc;
        }
        double p = 0.0;
        for (int tt = t; tt < RESN; tt += 1024) p += w[tt] * w[tt];
        p = wave_sum_f64(p);
        if (lane == 0) red[wv] = p;
        __syncthreads();
        if (t == 0) {
            double s = 0.0;
            for (int z = 0; z < 16; ++z) s += red[z];
            red[0] = sqrt(s);
        }
        __syncthreads();
        const double beta = red[0];
        if (t < RESN) {
            g_q[k + 1][t]  = w[t] / beta;
            g_qd[k + 1][t] = dwv[t] / beta;
        }
        __syncthreads();
    }
}

// ---------------- 5) merged output kernel: blocks 0..999 landscape, 1000..1003 poly fit ----------------
__global__ void __launch_bounds__(256) k_out(float* __restrict__ out) {
    if (blockIdx.x < (NB * RESN) / 4) {
        // ---- landscape: one wave per (b, grid point) ----
        const int wave = (blockIdx.x * blockDim.x + threadIdx.x) >> 6;
        const int lane = threadIdx.x & 63;
        const int b = wave / RESN, tt = wave % RESN;
        const int cnt = g_pcnt[b];
        const float smn = g_smin[b], smx = g_smax[b];
        const float stepg = (smx - smn) / 999.0f;
        const float g = (tt == RESN - 1) ? smx : smn + (float)tt * stepg;
        const float SQ2 = 1.41421356f;           // f32 sqrt(2), as reference
        float t5[5] = {0.f, 0.f, 0.f, 0.f, 0.f};
        const float* __restrict__ pb = g_pb[b];
        const float* __restrict__ pd = g_pd[b];
        for (int e = lane; e < cnt; e += 64) {
            float v = fminf(g - pb[e], pd[e] - g);
            v = v > 0.f ? v : 0.f;
            v *= SQ2;
            if (v > t5[4]) {
                t5[4] = v;
                #pragma unroll
                for (int z = 4; z > 0; --z)
                    if (t5[z] > t5[z - 1]) { const float tmp = t5[z - 1]; t5[z - 1] = t5[z]; t5[z] = tmp; }
            }
        }
        // butterfly merge of sorted-desc top-5 lists
        for (int off = 1; off < 64; off <<= 1) {
            float bv[5];
            #pragma unroll
            for (int z = 0; z < 5; ++z) bv[z] = __shfl_xor(t5[z], off, 64);
            float o[5]; int ia = 0, ib = 0;
            #pragma unroll
            for (int z = 0; z < 5; ++z) {
                const bool ta = (ib >= 5) || (ia < 5 && t5[ia] >= bv[ib]);
                o[z] = ta ? t5[ia++] : bv[ib++];
            }
            #pragma unroll
            for (int z = 0; z < 5; ++z) t5[z] = o[z];
        }
        if (lane == 0) {
            const float land = (t5[0] + t5[1] + t5[2] + t5[3] + t5[4]) / 5.0f;
            for (int rep = 0; rep < BREP; ++rep)
                out[(rep * NB + b) * RESN + tt] = land;
        }
        return;
    }
    // ---- polynomial fit outputs ----
    const int b = blockIdx.x - (NB * RESN) / 4, t = threadIdx.x;
    float* oy = out + BREP * NB * RESN;
    float* od = out + 2 * BREP * NB * RESN;
    if (g_ws0.bnz == 0) {
        // betti == 0 everywhere -> coef == 0 -> yvals/fderiv exactly 0
        for (int tt = t; tt < RESN; tt += 256) {
            for (int rep = 0; rep < BREP; ++rep) {
                oy[(rep * NB + b) * RESN + tt] = 0.f;
                if (tt >= SAMP && tt < RESN - SAMP)
                    od[(rep * NB + b) * (RESN - 2 * SAMP) + (tt - SAMP)] = 0.f;
            }
        }
        return;
    }
    const int lane = t & 63, wv = t >> 6;  // 4 waves
    __shared__ double dk[NMODE];
    __shared__ float  bet[RESN];
    for (int tt = t; tt < RESN; tt += 256) bet[tt] = g_betti[b * RESN + tt];
    __syncthreads();
    for (int k = wv; k < NMODE; k += 4) {
        double p = 0.0;
        for (int tt = lane; tt < RESN; tt += 64) p += (double)bet[tt] * g_q[k][tt];
        p = wave_sum_f64(p);
        if (lane == 0) dk[k] = p;
    }
    __syncthreads();
    const double scale = 2.0 / 999.0;
    for (int tt = t; tt < RESN; tt += 256) {
        double y = 0.0, d = 0.0;
        for (int k = 0; k < NMODE; ++k) {
            y += dk[k] * g_q[k][tt];
            d += dk[k] * g_qd[k][tt];
        }
        const float yv = (float)y;
        const float fd = (float)(fabs(d) * scale);
        for (int rep = 0; rep < BREP; ++rep) {
            oy[(rep * NB + b) * RESN + tt] = yv;
            if (tt >= SAMP && tt < RESN - SAMP)
                od[(rep * NB + b) * (RESN - 2 * SAMP) + (tt - SAMP)] = fd;
        }
    }
}

// ---------------- launcher ----------------
extern "C" void kernel_launch(void* const* d_in, const int* in_sizes, int n_in,
                              void* d_out, int out_size, void* d_ws, size_t ws_size,
                              hipStream_t stream) {
    const int*   ei  = (const int*)d_in[1];    // edge_index (2, 160000)
    const float* ea  = (const float*)d_in[2];  // edge_attr  (160000, 1)
    float*       out = (float*)d_out;          // [land 32x1000 | yvals 32x1000 | fderiv 32x900]

    void* ws0 = nullptr;
    hipGetSymbolAddress(&ws0, HIP_SYMBOL(g_ws0));          // address query only: capture-safe
    hipMemsetAsync(ws0, 0, sizeof(WS0), stream);           // adj + bnz = 0

    k_scatter<<<(NEDGE + 255) / 256, 256, 0, stream>>>(ei, ea);
    k_death1<<<(NB * NROI * NROI + 255) / 256, 256, 0, stream>>>();
    k_prim<<<NB, 64, 0, stream>>>();
    k_basis<<<1, 1024, 0, stream>>>();
    k_out<<<(NB * RESN) / 4 + NB, 256, 0, stream>>>(out);
}

// Round 5
// 168.267 us; speedup vs baseline: 1.4150x; 1.4150x over previous
//
#include <hip/hip_runtime.h>

// ---------------- problem constants ----------------
#define NROI  100
#define NB    4          // 400/100 diagonal blocks
#define NEDGE 160000
#define RESN  1000
#define SAMP  50
#define BREP  8          // batch tiling (B=8)
#define MDEG  44         // effective polynomial rank cutoff
#define NMODE (MDEG + 1)
#define BIGF  1.0e9f
#define PAIR_CAP 5056    // >= 100*99/2 - 99 masked pairs

// ---------------- static device workspace ----------------
__device__ float g_adj[NB * NROI * NROI];
__device__ float g_D[NB * NROI * NROI];
__device__ float g_death1[NB * NROI * NROI];
__device__ float g_betti[NB * RESN];
__device__ float g_pb[NB][PAIR_CAP];
__device__ float g_pd[NB][PAIR_CAP];
__device__ int   g_pcnt[NB];
__device__ float g_smin[NB], g_smax[NB];
__device__ int   g_bnz;              // any nonzero betti? (gates basis/fit)
__device__ double g_q[NMODE][RESN];  // orthonormal poly basis values
__device__ double g_qd[NMODE][RESN]; // derivatives d/dx

// ---------------- helpers ----------------
__device__ inline double wave_sum_f64(double p) {
    for (int off = 32; off > 0; off >>= 1) p += __shfl_xor(p, off, 64);
    return p;
}

// ---------------- 1) zero accumulators ----------------
__global__ void k_zero() {
    const int tid = blockIdx.x * blockDim.x + threadIdx.x;
    if (tid < NB * NROI * NROI) g_adj[tid] = 0.f;
    if (tid == 0) g_bnz = 0;
}

// ---------------- 2) scatter-add diagonal-block edges ----------------
__global__ void k_scatter(const int* __restrict__ ei, const float* __restrict__ ea) {
    const int e = blockIdx.x * blockDim.x + threadIdx.x;
    if (e >= NEDGE) return;
    const int r = ei[e], c = ei[NEDGE + e];
    const int br = r / NROI, bc = c / NROI;
    if (br == bc)
        atomicAdd(&g_adj[br * NROI * NROI + (r - br * NROI) * NROI + (c - bc * NROI)], ea[e]);
}

// ---------------- 3) D = max(1 - adj, 0) ----------------
__global__ void k_transform() {
    const int tid = blockIdx.x * blockDim.x + threadIdx.x;
    if (tid >= NB * NROI * NROI) return;
    const float d = 1.f - g_adj[tid];
    g_D[tid] = d > 0.f ? d : 0.f;
}

// ---------------- 4) H1 deaths: T[i,j] = min_k!=i,j max(D[i,k],D[j,k]); death1 = max(D,T) ----------------
// fmin/fmax are exact selections -> any association is bit-identical to the reference.
__global__ void k_death1() {
    const int tid = blockIdx.x * blockDim.x + threadIdx.x;
    if (tid >= NB * NROI * NROI) return;
    const int b  = tid / (NROI * NROI);
    const int ij = tid % (NROI * NROI);
    const int i = ij / NROI, j = ij % NROI;
    const float* __restrict__ ri = g_D + b * NROI * NROI + i * NROI;
    const float* __restrict__ rj = g_D + b * NROI * NROI + j * NROI;
    float Tm = BIGF;
    for (int k = 0; k < NROI; k += 4) {
        const float4 a = *(const float4*)(ri + k);
        const float4 c = *(const float4*)(rj + k);
        float m0 = (k + 0 == i || k + 0 == j) ? BIGF : fmaxf(a.x, c.x);
        float m1 = (k + 1 == i || k + 1 == j) ? BIGF : fmaxf(a.y, c.y);
        float m2 = (k + 2 == i || k + 2 == j) ? BIGF : fmaxf(a.z, c.z);
        float m3 = (k + 3 == i || k + 3 == j) ? BIGF : fmaxf(a.w, c.w);
        Tm = fminf(Tm, fminf(fminf(m0, m1), fminf(m2, m3)));
    }
    g_death1[tid] = fmaxf(ri[j], Tm);
}

// ---------------- 5) single-wave Prim; column-major zero bitmasks, pure VALU+ballot chain ----------------
__global__ void __launch_bounds__(64) k_prim() {
    const int b = blockIdx.x, lane = threadIdx.x;
    const float* __restrict__ Db = g_D + b * NROI * NROI;
    __shared__ float Dl[NROI * NROI];
    __shared__ float deathsL[NROI - 1];
    __shared__ int   vsL[NROI - 1], usL[NROI - 1];
    __shared__ int   parL[NROI];
    __shared__ unsigned char mstL[NROI * NROI];
    __shared__ int cntL;
    // stage D into LDS (2500 float4)
    for (int i = lane; i < NROI * NROI / 4; i += 64)
        ((float4*)Dl)[i] = ((const float4*)Db)[i];
    for (int i = lane; i < NROI * NROI / 4; i += 64) ((unsigned int*)mstL)[i] = 0;
    for (int s = lane; s < NROI - 1; s += 64) { deathsL[s] = 0.f; usL[s] = 0; }
    if (lane == 0) cntL = 0;
    __syncthreads();

    const int  i1   = 64 + lane;
    const bool has1 = (i1 < NROI);
    // column-major zero bitmasks: lane t holds column t (zc0) and column t+64 (zc1);
    // dword d, bit q <-> row j = 32d+q. Reads Dl[j*NROI+lane]: consecutive lanes ->
    // consecutive addresses -> conflict-free.
    unsigned int zc0[4], zc1[4];
    #pragma unroll
    for (int d = 0; d < 4; ++d) {
        unsigned int a = 0, c = 0;
        const int qmax = (d == 3) ? (NROI - 96) : 32;
        for (int q = 0; q < qmax; ++q) {
            const int j = d * 32 + q;
            a |= (Dl[j * NROI + lane] == 0.f ? 1u : 0u) << q;
            if (has1) c |= (Dl[j * NROI + i1] == 0.f ? 1u : 0u) << q;
        }
        zc0[d] = a; zc1[d] = c;
    }

    // candidate mask C (nodes with a zero edge from tree), tree mask T  (in-register, all lanes)
    unsigned long long Clo = __ballot((zc0[0] & 1u) != 0u);   // row 0 = bit 0 of each column
    unsigned long long Chi = __ballot((zc1[0] & 1u) != 0u);
    unsigned long long Tlo = 1ull, Thi = 0ull;
    bool it0 = (lane == 0), it1 = false;
    bool cand0 = (zc0[0] & 1u) != 0u;            // mind==0 already (from row 0)
    bool cand1 = (zc1[0] & 1u) != 0u;
    int  par0 = 0, par1 = 0;                     // first zero-offerer (frozen once cand)

    for (int step = 0; step < NROI - 1; ++step) {
        const unsigned long long alo = Clo & ~Tlo, ahi = Chi & ~Thi;
        int j;
        if (alo | ahi) {
            // jnp.argmin first-index == first not-in-tree node with mind==0 (D >= 0 always)
            j = alo ? (__ffsll(alo) - 1) : (63 + __ffsll(ahi));
        } else {
            // general fallback: replay mind/parent over tree insertion order, exact butterfly argmin
            float m0 = Dl[lane]; int p0 = 0;
            float m1 = has1 ? Dl[i1] : BIGF; int p1 = 0;
            for (int s = 0; s < step; ++s) {
                const int q = vsL[s];
                const float d0 = Dl[q * NROI + lane];
                if (d0 < m0) { m0 = d0; p0 = q; }     // strict <, as reference
                if (has1) {
                    const float d1 = Dl[q * NROI + i1];
                    if (d1 < m1) { m1 = d1; p1 = q; }
                }
            }
            const float v0 = it0 ? BIGF : m0;
            const float v1 = (has1 && !it1) ? m1 : BIGF;
            float vv; int idx, pw;
            if (v0 <= v1) { vv = v0; idx = lane; pw = p0; } else { vv = v1; idx = i1; pw = p1; }
            #pragma unroll
            for (int off = 1; off < 64; off <<= 1) {
                const float ov = __shfl_xor(vv, off, 64);
                const int   oi = __shfl_xor(idx, off, 64);
                const int   op = __shfl_xor(pw, off, 64);
                if (ov < vv || (ov == vv && oi < idx)) { vv = ov; idx = oi; pw = op; }
            }
            j = idx;
            if (lane == 0) { deathsL[step] = vv; usL[step] = pw; }
        }
        if (lane == 0) vsL[step] = j;
        if (j < 64) Tlo |= 1ull << j; else Thi |= 1ull << (j - 64);
        if (lane == j) it0 = true;
        if (i1 == j)   it1 = true;
        // extract bit j of MY columns (same-lane VALU: cndmask chain + shift)
        const int d = j >> 5, sh = j & 31;
        const unsigned int w0 = (d == 0) ? zc0[0] : (d == 1) ? zc0[1] : (d == 2) ? zc0[2] : zc0[3];
        const unsigned int w1 = (d == 0) ? zc1[0] : (d == 1) ? zc1[1] : (d == 2) ? zc1[2] : zc1[3];
        const bool bit0 = (w0 >> sh) & 1u;
        const bool bit1 = (w1 >> sh) & 1u;
        // row j's zero mask across columns, via ballot (no LDS, no readlane)
        Clo |= __ballot(bit0);
        Chi |= __ballot(bit1);
        // parent = first zero-offerer; frozen once candidate; in-tree nodes never update
        if (bit0 && !cand0 && !it0) { par0 = j; cand0 = true; }
        if (bit1 && !cand1 && !it1) { par1 = j; cand1 = true; }
    }
    // final parents -> LDS, then resolve u per step and build MST bitmap
    parL[lane] = par0;
    if (has1) parL[i1] = par1;
    __syncthreads();
    for (int s = lane; s < NROI - 1; s += 64) {
        const int j = vsL[s];
        const int u = (deathsL[s] > 0.f) ? usL[s] : parL[j];  // zero-death => parent = first-zero-offerer
        mstL[u * NROI + j] = 1;
        mstL[j * NROI + u] = 1;
    }
    __syncthreads();

    // masked pair compaction + smin/smax
    float mn = BIGF, mx = -BIGF;
    for (int e = lane; e < NROI * NROI; e += 64) {
        const int i = e / NROI, jj = e % NROI;
        if (i < jj && !mstL[e]) {
            const float bv = Dl[e];
            const float dv = g_death1[b * NROI * NROI + e];
            mn = fminf(mn, bv); mx = fmaxf(mx, dv);
            const int pos = atomicAdd(&cntL, 1);
            g_pb[b][pos] = bv; g_pd[b][pos] = dv;
        }
    }
    #pragma unroll
    for (int off = 1; off < 64; off <<= 1) {
        mn = fminf(mn, __shfl_xor(mn, off, 64));
        mx = fmaxf(mx, __shfl_xor(mx, off, 64));
    }
    __syncthreads();
    if (lane == 0) { g_smin[b] = mn; g_smax[b] = mx; g_pcnt[b] = cntL; }

    // dmax + betti (H0)
    float dmax = -1.f;
    for (int s = lane; s < NROI - 1; s += 64) dmax = fmaxf(dmax, deathsL[s]);
    #pragma unroll
    for (int off = 1; off < 64; off <<= 1) dmax = fmaxf(dmax, __shfl_xor(dmax, off, 64));
    const float stepg = dmax / 999.0f;       // f32 linspace step, start = 0
    for (int tt = lane; tt < RESN; tt += 64) {
        const float g = (tt == RESN - 1) ? dmax : (float)tt * stepg;
        int cnt2 = 0;
        for (int s2 = 0; s2 < NROI - 1; ++s2) cnt2 += (g < deathsL[s2]) ? 1 : 0;
        g_betti[b * RESN + tt] = (float)cnt2;
    }
    if (lane == 0 && dmax > 0.f) atomicOr(&g_bnz, 1);
}

// ---------------- 6) persistence landscape: one wave per (b, grid point) ----------------
__global__ void __launch_bounds__(256) k_land(float* __restrict__ out) {
    const int wave = (blockIdx.x * blockDim.x + threadIdx.x) >> 6;
    const int lane = threadIdx.x & 63;
    const int b = wave / RESN, tt = wave % RESN;
    if (b >= NB) return;
    const int cnt = g_pcnt[b];
    const float smn = g_smin[b], smx = g_smax[b];
    const float stepg = (smx - smn) / 999.0f;
    const float g = (tt == RESN - 1) ? smx : smn + (float)tt * stepg;
    const float SQ2 = 1.41421356f;           // f32 sqrt(2), as reference
    float t5[5] = {0.f, 0.f, 0.f, 0.f, 0.f};
    const float* __restrict__ pb = g_pb[b];
    const float* __restrict__ pd = g_pd[b];
    for (int e = lane; e < cnt; e += 64) {
        float v = fminf(g - pb[e], pd[e] - g);
        v = v > 0.f ? v : 0.f;
        v *= SQ2;
        if (v > t5[4]) {
            t5[4] = v;
            #pragma unroll
            for (int z = 4; z > 0; --z)
                if (t5[z] > t5[z - 1]) { const float tmp = t5[z - 1]; t5[z - 1] = t5[z]; t5[z] = tmp; }
        }
    }
    // butterfly merge of sorted-desc top-5 lists
    for (int off = 1; off < 64; off <<= 1) {
        float bv[5];
        #pragma unroll
        for (int z = 0; z < 5; ++z) bv[z] = __shfl_xor(t5[z], off, 64);
        float o[5]; int ia = 0, ib = 0;
        #pragma unroll
        for (int z = 0; z < 5; ++z) {
            const bool ta = (ib >= 5) || (ia < 5 && t5[ia] >= bv[ib]);
            o[z] = ta ? t5[ia++] : bv[ib++];
        }
        #pragma unroll
        for (int z = 0; z < 5; ++z) t5[z] = o[z];
    }
    if (lane == 0) {
        const float land = (t5[0] + t5[1] + t5[2] + t5[3] + t5[4]) / 5.0f;
        for (int rep = 0; rep < BREP; ++rep)
            out[(rep * NB + b) * RESN + tt] = land;
    }
}

// ---------------- 7) orthonormal polynomial basis (skipped when betti==0) ----------------
__global__ void __launch_bounds__(1024) k_basis() {
    if (g_bnz == 0) return;   // degenerate H0 branch: fit is exactly zero, basis unused
    const int t = threadIdx.x;
    const int lane = t & 63, wv = t >> 6;  // 16 waves
    __shared__ double xs[RESN];
    __shared__ double w[RESN], dwv[RESN];
    __shared__ double cj[NMODE], ctot[NMODE];
    __shared__ double red[16];
    if (t < RESN) {
        xs[t] = (2.0 * (double)t - 999.0) / 999.0;
        const double q0 = 1.0 / sqrt(1000.0);
        g_q[0][t] = q0;
        g_qd[0][t] = 0.0;
    }
    __syncthreads();
    for (int k = 0; k < MDEG; ++k) {
        if (t < RESN) {
            w[t]   = xs[t] * g_q[k][t];
            dwv[t] = g_q[k][t] + xs[t] * g_qd[k][t];
        }
        if (t < NMODE) ctot[t] = 0.0;
        __syncthreads();
        for (int round = 0; round < 2; ++round) {   // CGS twice == stable
            for (int j = wv; j <= k; j += 16) {
                double p = 0.0;
                for (int tt = lane; tt < RESN; tt += 64) p += w[tt] * g_q[j][tt];
                p = wave_sum_f64(p);
                if (lane == 0) cj[j] = p;
            }
            __syncthreads();
            if (t < RESN) {
                double acc = w[t];
                for (int j = 0; j <= k; ++j) acc -= cj[j] * g_q[j][t];
                w[t] = acc;
            }
            if (t <= k) ctot[t] += cj[t];
            __syncthreads();
        }
        if (t < RESN) {
            double acc = dwv[t];
            for (int j = 0; j <= k; ++j) acc -= ctot[j] * g_qd[j][t];
            dwv[t] = acc;
        }
        double p = 0.0;
        for (int tt = t; tt < RESN; tt += 1024) p += w[tt] * w[tt];
        p = wave_sum_f64(p);
        if (lane == 0) red[wv] = p;
        __syncthreads();
        if (t == 0) {
            double s = 0.0;
            for (int z = 0; z < 16; ++z) s += red[z];
            red[0] = sqrt(s);
        }
        __syncthreads();
        const double beta = red[0];
        if (t < RESN) {
            g_q[k + 1][t]  = w[t] / beta;
            g_qd[k + 1][t] = dwv[t] / beta;
        }
        __syncthreads();
    }
}

// ---------------- 8) fit: project betti onto basis; emit yvals and |derivative|*scale ----------------
__global__ void __launch_bounds__(256) k_fit(float* __restrict__ out) {
    const int b = blockIdx.x, t = threadIdx.x;
    float* oy = out + BREP * NB * RESN;
    float* od = out + 2 * BREP * NB * RESN;
    if (g_bnz == 0) {
        // betti == 0 everywhere -> coef == 0 -> yvals/fderiv exactly 0
        for (int tt = t; tt < RESN; tt += 256) {
            for (int rep = 0; rep < BREP; ++rep) {
                oy[(rep * NB + b) * RESN + tt] = 0.f;
                if (tt >= SAMP && tt < RESN - SAMP)
                    od[(rep * NB + b) * (RESN - 2 * SAMP) + (tt - SAMP)] = 0.f;
            }
        }
        return;
    }
    const int lane = t & 63, wv = t >> 6;  // 4 waves
    __shared__ double dk[NMODE];
    __shared__ float  bet[RESN];
    for (int tt = t; tt < RESN; tt += 256) bet[tt] = g_betti[b * RESN + tt];
    __syncthreads();
    for (int k = wv; k < NMODE; k += 4) {
        double p = 0.0;
        for (int tt = lane; tt < RESN; tt += 64) p += (double)bet[tt] * g_q[k][tt];
        p = wave_sum_f64(p);
        if (lane == 0) dk[k] = p;
    }
    __syncthreads();
    const double scale = 2.0 / 999.0;
    for (int tt = t; tt < RESN; tt += 256) {
        double y = 0.0, d = 0.0;
        for (int k = 0; k < NMODE; ++k) {
            y += dk[k] * g_q[k][tt];
            d += dk[k] * g_qd[k][tt];
        }
        const float yv = (float)y;
        const float fd = (float)(fabs(d) * scale);
        for (int rep = 0; rep < BREP; ++rep) {
            oy[(rep * NB + b) * RESN + tt] = yv;
            if (tt >= SAMP && tt < RESN - SAMP)
                od[(rep * NB + b) * (RESN - 2 * SAMP) + (tt - SAMP)] = fd;
        }
    }
}

// ---------------- launcher ----------------
extern "C" void kernel_launch(void* const* d_in, const int* in_sizes, int n_in,
                              void* d_out, int out_size, void* d_ws, size_t ws_size,
                              hipStream_t stream) {
    const int*   ei  = (const int*)d_in[1];    // edge_index (2, 160000)
    const float* ea  = (const float*)d_in[2];  // edge_attr  (160000, 1)
    float*       out = (float*)d_out;          // [land 32x1000 | yvals 32x1000 | fderiv 32x900]

    k_zero<<<(NB * NROI * NROI + 255) / 256, 256, 0, stream>>>();
    k_scatter<<<(NEDGE + 255) / 256, 256, 0, stream>>>(ei, ea);
    k_transform<<<(NB * NROI * NROI + 255) / 256, 256, 0, stream>>>();
    k_death1<<<(NB * NROI * NROI + 255) / 256, 256, 0, stream>>>();
    k_prim<<<NB, 64, 0, stream>>>();
    k_land<<<(NB * RESN + 3) / 4, 256, 0, stream>>>(out);
    k_basis<<<1, 1024, 0, stream>>>();
    k_fit<<<NB, 256, 0, stream>>>(out);
}